// Round 2
// baseline (180.376 us; speedup 1.0000x reference)
//
#include <hip/hip_runtime.h>
#include <hip/hip_bf16.h>

#define H 500
#define D_IN 512
#define D_OUT 100
#define STEPS 49

typedef _Float16 h2_t __attribute__((ext_vector_type(2)));
typedef _Float16 h4_t __attribute__((ext_vector_type(4)));
typedef _Float16 h8_t __attribute__((ext_vector_type(8)));

#if defined(__has_builtin)
#if __has_builtin(__builtin_amdgcn_fdot2)
#define HAVE_FDOT2 1
#endif
#endif

__device__ __forceinline__ float fdot2f(h2_t a, h2_t b, float c) {
#ifdef HAVE_FDOT2
    return __builtin_amdgcn_fdot2(a, b, c, false);
#else
    return c + (float)a[0] * (float)b[0] + (float)a[1] * (float)b[1];
#endif
}

// ---------------- K1: xproj[t][r] = b_ih[r]+b_hh[r] + sum_d seq[t][d]*W_ih[r][d]
// seq[t][d] = x[d*49 + t]
__global__ void k1_xproj(const float* __restrict__ x, const float* __restrict__ W_ih,
                         const float* __restrict__ b_ih, const float* __restrict__ b_hh,
                         float* __restrict__ xproj) {
    const int r = blockIdx.x;       // 0..499
    const int lane = threadIdx.x;   // 0..63
    float w[8];
#pragma unroll
    for (int k = 0; k < 8; k++) w[k] = W_ih[r * D_IN + k * 64 + lane];
    float p[STEPS];
#pragma unroll
    for (int t = 0; t < STEPS; t++) p[t] = 0.f;
#pragma unroll
    for (int k = 0; k < 8; k++) {
        const float* xr = x + (size_t)(k * 64 + lane) * STEPS;
#pragma unroll
        for (int t = 0; t < STEPS; t++) p[t] = fmaf(w[k], xr[t], p[t]);
    }
#pragma unroll
    for (int t = 0; t < STEPS; t++) {
        float v = p[t];
        v += __shfl_xor(v, 32); v += __shfl_xor(v, 16); v += __shfl_xor(v, 8);
        v += __shfl_xor(v, 4);  v += __shfl_xor(v, 2);  v += __shfl_xor(v, 1);
        p[t] = v;
    }
    if (lane == 0) {
        const float b = b_ih[r] + b_hh[r];
        for (int t = 0; t < STEPS; t++) xproj[t * H + r] = p[t] + b;
    }
}

// ---------------- K2: single-workgroup recurrent scan, weights register-resident (f16).
// 512 threads = 8 waves on ONE CU. Wave w: column slice [64w, 64w+64); lane l: rows
// {l+64k, k=0..7} (512-padded). Per thread: cols 0..59 of slice in 240 h2 VGPRs,
// cols 60..63 in LDS tail Wl. h kept as f16[512] in LDS (pad cols are 0, which
// nullifies any clamped/garbage pad weights). Partials reduced via pbuf[w][k][l]
// (bank-conflict-free b32 pattern both sides). Two __syncthreads per step.
__global__ __launch_bounds__(512, 1) void k2_scan(
    const float* __restrict__ hidden0, const float* __restrict__ W_hh,
    const float* __restrict__ xproj, float* __restrict__ Hs) {
    __shared__ __align__(16) _Float16 h16[512];
    __shared__ uint2 Wl[8 * 512];      // [w][row]: slice cols 60..63 as 2x h2
    __shared__ float pbuf[8 * 512];    // [w][k][l]

    const int tid = threadIdx.x;
    const int w = tid >> 6, l = tid & 63;

    // ---- one-time: load + convert weights ----
    h2_t wreg[8][30];
#pragma unroll
    for (int k = 0; k < 8; k++) {
        const int r = l + 64 * k;
        const int rr = (r < H) ? r : (H - 1);
        const float* rowp = W_hh + rr * H;
#pragma unroll
        for (int j4 = 0; j4 < 15; j4++) {
            int col = w * 64 + 4 * j4;
            if (col > 496) col = 496;              // stay in-bounds; pad cols hit h==0
            const float4 v = *(const float4*)(rowp + col);
            wreg[k][2 * j4]     = h2_t{(_Float16)v.x, (_Float16)v.y};
            wreg[k][2 * j4 + 1] = h2_t{(_Float16)v.z, (_Float16)v.w};
        }
        int colt = w * 64 + 60;
        if (colt > 496) colt = 496;
        const float4 vt = *(const float4*)(rowp + colt);
        const h2_t t0 = {(_Float16)vt.x, (_Float16)vt.y};
        const h2_t t1 = {(_Float16)vt.z, (_Float16)vt.w};
        Wl[(w << 9) + r] = uint2{__builtin_bit_cast(unsigned, t0),
                                 __builtin_bit_cast(unsigned, t1)};
    }
    h16[tid] = (tid < H) ? (_Float16)hidden0[tid] : (_Float16)0.f;
    __syncthreads();

    const int rs = (tid < H) ? tid : (H - 1);
    for (int t = 0; t < STEPS; t++) {
        const float xp = xproj[t * H + rs];        // prefetched; used after barrier

        float a[8] = {0.f, 0.f, 0.f, 0.f, 0.f, 0.f, 0.f, 0.f};
        const h8_t* hs8 = (const h8_t*)(h16 + w * 64);
#pragma unroll
        for (int B = 0; B < 7; B++) {
            const h8_t hv = hs8[B];                // broadcast ds_read_b128
#pragma unroll
            for (int p = 0; p < 4; p++) {
                const h2_t hp = {hv[2 * p], hv[2 * p + 1]};
#pragma unroll
                for (int k = 0; k < 8; k++)
                    a[k] = fdot2f(wreg[k][4 * B + p], hp, a[k]);
            }
        }
        {   // slice cols 56..59 (reg) ...
            const h4_t hv4 = *(const h4_t*)(h16 + w * 64 + 56);
            const h2_t hp0 = {hv4[0], hv4[1]}, hp1 = {hv4[2], hv4[3]};
#pragma unroll
            for (int k = 0; k < 8; k++) {
                a[k] = fdot2f(wreg[k][28], hp0, a[k]);
                a[k] = fdot2f(wreg[k][29], hp1, a[k]);
            }
        }
        {   // ... and 60..63 (LDS tail)
            const h4_t ht = *(const h4_t*)(h16 + w * 64 + 60);
            const h2_t hp0 = {ht[0], ht[1]}, hp1 = {ht[2], ht[3]};
#pragma unroll
            for (int k = 0; k < 8; k++) {
                const uint2 wl2 = Wl[(w << 9) + l + 64 * k];
                a[k] = fdot2f(__builtin_bit_cast(h2_t, wl2.x), hp0, a[k]);
                a[k] = fdot2f(__builtin_bit_cast(h2_t, wl2.y), hp1, a[k]);
            }
        }
#pragma unroll
        for (int k = 0; k < 8; k++) pbuf[(w << 9) + (k << 6) + l] = a[k];
        __syncthreads();

        // reduce: thread tid owns row tid; its partials sit at [w2][tid>>6][tid&63]
        float s = 0.f;
        const int l0 = tid & 63, k0 = tid >> 6;
#pragma unroll
        for (int w2 = 0; w2 < 8; w2++) s += pbuf[(w2 << 9) + (k0 << 6) + l0];
        const float hval = tanhf(s + xp);
        h16[tid] = (tid < H) ? (_Float16)hval : (_Float16)0.f;  // keep pads zero
        if (tid < H) Hs[t * 512 + tid] = hval;
        __syncthreads();
    }
}

// ---------------- K3: out[t][o] = tanh(b_out[o] + sum_c Hs[t][c]*W_out[o][c])
__global__ void k3_out(const float* __restrict__ Hs, const float* __restrict__ W_out,
                       const float* __restrict__ b_out, float* __restrict__ out) {
    const int t = blockIdx.x, o = threadIdx.x;
    if (o < D_OUT) {
        const float4* wr = (const float4*)(W_out + o * H);
        const float4* hr = (const float4*)(Hs + t * 512);
        float acc = b_out[o];
#pragma unroll 5
        for (int i = 0; i < 125; i++) {
            const float4 wv = wr[i];
            const float4 hv = hr[i];
            acc = fmaf(wv.x, hv.x, acc);
            acc = fmaf(wv.y, hv.y, acc);
            acc = fmaf(wv.z, hv.z, acc);
            acc = fmaf(wv.w, hv.w, acc);
        }
        out[t * D_OUT + o] = tanhf(acc);
    }
}

extern "C" void kernel_launch(void* const* d_in, const int* in_sizes, int n_in,
                              void* d_out, int out_size, void* d_ws, size_t ws_size,
                              hipStream_t stream) {
    const float* x       = (const float*)d_in[0];
    const float* hidden0 = (const float*)d_in[1];
    const float* W_ih    = (const float*)d_in[2];
    const float* W_hh    = (const float*)d_in[3];
    const float* b_ih    = (const float*)d_in[4];
    const float* b_hh    = (const float*)d_in[5];
    const float* W_out   = (const float*)d_in[6];
    const float* b_out   = (const float*)d_in[7];
    float* out = (float*)d_out;

    char* ws = (char*)d_ws;
    float* xproj = (float*)ws;                 // 49*500*4 = 98000 -> pad 98304
    float* Hs    = (float*)(ws + 98304);       // 49*512*4 = 100352

    k1_xproj<<<H, 64, 0, stream>>>(x, W_ih, b_ih, b_hh, xproj);
    k2_scan<<<1, 512, 0, stream>>>(hidden0, W_hh, xproj, Hs);
    k3_out<<<STEPS, 128, 0, stream>>>(Hs, W_out, b_out, out);
}

// Round 3
// 106.076 us; speedup vs baseline: 1.7004x; 1.7004x over previous
//
#include <hip/hip_runtime.h>
#include <hip/hip_bf16.h>

#define H 500
#define D_IN 512
#define D_OUT 100
#define STEPS 49

typedef _Float16 h2_t __attribute__((ext_vector_type(2)));

#if defined(__has_builtin)
#if __has_builtin(__builtin_amdgcn_fdot2)
#define HAVE_FDOT2 1
#endif
#endif

__device__ __forceinline__ float fdot2f(h2_t a, h2_t b, float c) {
#ifdef HAVE_FDOT2
    return __builtin_amdgcn_fdot2(a, b, c, false);
#else
    return c + (float)a[0] * (float)b[0] + (float)a[1] * (float)b[1];
#endif
}
__device__ __forceinline__ h2_t bch2(unsigned u) { return __builtin_bit_cast(h2_t, u); }

// ---------------- K0: pack W_hh (f32 [500][500]) into f16 blobs laid out so that
// K2's per-thread register/LDS loads are fully coalesced. K2 thread tid=(w,l)
// owns rows r=l+64k (k=0..7) of col-slice [64w, 64w+64). Slice h2-pairs 0..25
// (cols 0..51) -> registers; pairs 26..29 (cols 52..59) -> LDS plane A (uint4);
// pairs 30..31 (cols 60..63) -> LDS plane B (uint2). Pads (row/col >= 500) = 0.
__global__ void k0_pack(const float* __restrict__ W_hh,
                        uint4* __restrict__ blobW, uint2* __restrict__ blobW2,
                        uint4* __restrict__ blobTA, uint2* __restrict__ blobTB) {
    const int T = blockIdx.x * 256 + threadIdx.x;   // 0..4095
    const int k = T >> 9, tid = T & 511;
    const int w = tid >> 6, l = tid & 63;
    const int row = l + 64 * k;
    const int c0 = w * 64;

    _Float16 v[64];
    if (row < H && w < 7) {            // cols c0..c0+63 all < 500
        const float4* src = (const float4*)(W_hh + row * H + c0);  // 16B aligned
#pragma unroll
        for (int q = 0; q < 16; q++) {
            const float4 f = src[q];
            v[4 * q + 0] = (_Float16)f.x; v[4 * q + 1] = (_Float16)f.y;
            v[4 * q + 2] = (_Float16)f.z; v[4 * q + 3] = (_Float16)f.w;
        }
    } else {
#pragma unroll
        for (int i = 0; i < 64; i++) {
            const int c = c0 + i;
            v[i] = (row < H && c < H) ? (_Float16)W_hh[row * H + c] : (_Float16)0.f;
        }
    }
    unsigned up[32];
#pragma unroll
    for (int i = 0; i < 32; i++) {
        h2_t p{v[2 * i], v[2 * i + 1]};
        up[i] = __builtin_bit_cast(unsigned, p);
    }
#pragma unroll
    for (int j4 = 0; j4 < 6; j4++) {
        uint4 u; u.x = up[4*j4]; u.y = up[4*j4+1]; u.z = up[4*j4+2]; u.w = up[4*j4+3];
        blobW[(k * 6 + j4) * 512 + tid] = u;
    }
    { uint2 u; u.x = up[24]; u.y = up[25]; blobW2[k * 512 + tid] = u; }
    { uint4 u; u.x = up[26]; u.y = up[27]; u.z = up[28]; u.w = up[29]; blobTA[k * 512 + tid] = u; }
    { uint2 u; u.x = up[30]; u.y = up[31]; blobTB[k * 512 + tid] = u; }
}

// ---------------- K1: xproj[t][r] = b_ih[r]+b_hh[r] + sum_d seq[t][d]*W_ih[r][d]
__global__ void k1_xproj(const float* __restrict__ x, const float* __restrict__ W_ih,
                         const float* __restrict__ b_ih, const float* __restrict__ b_hh,
                         float* __restrict__ xproj) {
    const int r = blockIdx.x;       // 0..499
    const int lane = threadIdx.x;   // 0..63
    float w[8];
#pragma unroll
    for (int k = 0; k < 8; k++) w[k] = W_ih[r * D_IN + k * 64 + lane];
    float p[STEPS];
#pragma unroll
    for (int t = 0; t < STEPS; t++) p[t] = 0.f;
#pragma unroll
    for (int k = 0; k < 8; k++) {
        const float* xr = x + (size_t)(k * 64 + lane) * STEPS;
#pragma unroll
        for (int t = 0; t < STEPS; t++) p[t] = fmaf(w[k], xr[t], p[t]);
    }
#pragma unroll
    for (int t = 0; t < STEPS; t++) {
        float v = p[t];
        v += __shfl_xor(v, 32); v += __shfl_xor(v, 16); v += __shfl_xor(v, 8);
        v += __shfl_xor(v, 4);  v += __shfl_xor(v, 2);  v += __shfl_xor(v, 1);
        p[t] = v;
    }
    if (lane == 0) {
        const float b = b_ih[r] + b_hh[r];
        for (int t = 0; t < STEPS; t++) xproj[t * H + r] = p[t] + b;
    }
}

// ---------------- K2: single-CU recurrent scan. 512 threads = 8 waves, exactly
// 2 waves/EU (pinned) -> 256-VGPR budget. Wave w owns col slice [64w,64w+64);
// lane l owns rows l+64k. 52 cols/row in regs (208 h2 VGPRs), 12 cols in LDS
// planes (conflict-free strides). h as f16[512] in LDS, pads zero.
__global__ __attribute__((amdgpu_flat_work_group_size(512, 512)))
__attribute__((amdgpu_waves_per_eu(2, 2)))
void k2_scan(const float* __restrict__ hidden0,
             const uint4* __restrict__ blobW, const uint2* __restrict__ blobW2,
             const uint4* __restrict__ blobTA, const uint2* __restrict__ blobTB,
             const float* __restrict__ xproj, float* __restrict__ Hs) {
    __shared__ uint4 WlA[8][512];               // 64KB  [w][r] cols 52..59
    __shared__ uint2 WlB[8][512];               // 32KB  [w][r] cols 60..63
    __shared__ float pbuf[8][512];              // 16KB  [w][r]
    __shared__ __align__(16) _Float16 h16[512]; // 1KB

    const int tid = threadIdx.x, w = tid >> 6, l = tid & 63;

    // ---- preload: coalesced f16 blob -> 208 weight VGPRs + LDS tail planes ----
    h2_t wreg[8][26];
#pragma unroll
    for (int k = 0; k < 8; k++) {
#pragma unroll
        for (int j4 = 0; j4 < 6; j4++) {
            const uint4 u = blobW[(k * 6 + j4) * 512 + tid];
            wreg[k][4 * j4 + 0] = bch2(u.x);
            wreg[k][4 * j4 + 1] = bch2(u.y);
            wreg[k][4 * j4 + 2] = bch2(u.z);
            wreg[k][4 * j4 + 3] = bch2(u.w);
        }
        const uint2 u2 = blobW2[k * 512 + tid];
        wreg[k][24] = bch2(u2.x);
        wreg[k][25] = bch2(u2.y);
        WlA[w][l + 64 * k] = blobTA[k * 512 + tid];
        WlB[w][l + 64 * k] = blobTB[k * 512 + tid];
    }
    h16[tid] = (tid < H) ? (_Float16)hidden0[tid] : (_Float16)0.f;
    __syncthreads();

    const int rs = (tid < H) ? tid : 0;
    for (int t = 0; t < STEPS; t++) {
        const float xp = xproj[t * H + rs];

        float a[8] = {0.f, 0.f, 0.f, 0.f, 0.f, 0.f, 0.f, 0.f};
        const uint4* hsl = (const uint4*)(h16 + w * 64);   // broadcast b128 reads
#pragma unroll
        for (int b = 0; b < 6; b++) {
            const uint4 hb = hsl[b];
            const h2_t hp0 = bch2(hb.x), hp1 = bch2(hb.y),
                       hp2 = bch2(hb.z), hp3 = bch2(hb.w);
#pragma unroll
            for (int k = 0; k < 8; k++) {
                a[k] = fdot2f(wreg[k][4 * b + 0], hp0, a[k]);
                a[k] = fdot2f(wreg[k][4 * b + 1], hp1, a[k]);
                a[k] = fdot2f(wreg[k][4 * b + 2], hp2, a[k]);
                a[k] = fdot2f(wreg[k][4 * b + 3], hp3, a[k]);
            }
        }
        const uint4 hb6 = hsl[6];
        const uint4 hb7 = hsl[7];
        const h2_t hp24 = bch2(hb6.x), hp25 = bch2(hb6.y);
        const h2_t hpA0 = bch2(hb6.z), hpA1 = bch2(hb6.w);
        const h2_t hpA2 = bch2(hb7.x), hpA3 = bch2(hb7.y);
        const h2_t hpB0 = bch2(hb7.z), hpB1 = bch2(hb7.w);
#pragma unroll
        for (int k = 0; k < 8; k++) {
            const int r = l + 64 * k;
            const uint4 ta = WlA[w][r];
            const uint2 tb = WlB[w][r];
            a[k] = fdot2f(wreg[k][24], hp24, a[k]);
            a[k] = fdot2f(wreg[k][25], hp25, a[k]);
            a[k] = fdot2f(bch2(ta.x), hpA0, a[k]);
            a[k] = fdot2f(bch2(ta.y), hpA1, a[k]);
            a[k] = fdot2f(bch2(ta.z), hpA2, a[k]);
            a[k] = fdot2f(bch2(ta.w), hpA3, a[k]);
            a[k] = fdot2f(bch2(tb.x), hpB0, a[k]);
            a[k] = fdot2f(bch2(tb.y), hpB1, a[k]);
        }
#pragma unroll
        for (int k = 0; k < 8; k++) pbuf[w][64 * k + l] = a[k];  // slot = row
        __syncthreads();

        float s = 0.f;
#pragma unroll
        for (int w2 = 0; w2 < 8; w2++) s += pbuf[w2][tid];
        const float hval = tanhf(s + xp);
        if (tid < H) Hs[t * 512 + tid] = hval;
        h16[tid] = (tid < H) ? (_Float16)hval : (_Float16)0.f;
        __syncthreads();
    }
}

// ---------------- K3: out[t][o] = tanh(b_out[o] + sum_c Hs[t][c]*W_out[o][c])
__global__ void k3_out(const float* __restrict__ Hs, const float* __restrict__ W_out,
                       const float* __restrict__ b_out, float* __restrict__ out) {
    const int t = blockIdx.x, o = threadIdx.x;
    if (o < D_OUT) {
        const float4* wr = (const float4*)(W_out + o * H);
        const float4* hr = (const float4*)(Hs + t * 512);
        float acc = b_out[o];
#pragma unroll 5
        for (int i = 0; i < 125; i++) {
            const float4 wv = wr[i];
            const float4 hv = hr[i];
            acc = fmaf(wv.x, hv.x, acc);
            acc = fmaf(wv.y, hv.y, acc);
            acc = fmaf(wv.z, hv.z, acc);
            acc = fmaf(wv.w, hv.w, acc);
        }
        out[t * D_OUT + o] = tanhf(acc);
    }
}

extern "C" void kernel_launch(void* const* d_in, const int* in_sizes, int n_in,
                              void* d_out, int out_size, void* d_ws, size_t ws_size,
                              hipStream_t stream) {
    const float* x       = (const float*)d_in[0];
    const float* hidden0 = (const float*)d_in[1];
    const float* W_ih    = (const float*)d_in[2];
    const float* W_hh    = (const float*)d_in[3];
    const float* b_ih    = (const float*)d_in[4];
    const float* b_hh    = (const float*)d_in[5];
    const float* W_out   = (const float*)d_in[6];
    const float* b_out   = (const float*)d_in[7];
    float* out = (float*)d_out;

    char* ws = (char*)d_ws;
    uint4* blobW  = (uint4*)(ws);             // 48*512*16 = 393216
    uint2* blobW2 = (uint2*)(ws + 393216);    // 8*512*8   =  32768
    uint4* blobTA = (uint4*)(ws + 425984);    // 8*512*16  =  65536
    uint2* blobTB = (uint2*)(ws + 491520);    // 8*512*8   =  32768
    float* xproj  = (float*)(ws + 524288);    // 49*500*4 -> 98304
    float* Hs     = (float*)(ws);             // 49*512*4 = 100352, aliases blobW
                                              // (blobW fully consumed in K2 preload
                                              //  before first Hs write; K0 rewrites
                                              //  blobW every launch)

    k0_pack<<<16, 256, 0, stream>>>(W_hh, blobW, blobW2, blobTA, blobTB);
    k1_xproj<<<H, 64, 0, stream>>>(x, W_ih, b_ih, b_hh, xproj);
    k2_scan<<<1, 512, 0, stream>>>(hidden0, blobW, blobW2, blobTA, blobTB, xproj, Hs);
    k3_out<<<STEPS, 128, 0, stream>>>(Hs, W_out, b_out, out);
}